// Round 13
// baseline (169.069 us; speedup 1.0000x reference)
//
#include <hip/hip_runtime.h>
#include <hip/hip_bf16.h>
#include <math.h>

// BahdanauAttention on MI355X (gfx950).
// query (16,64,1024) f32, keys (16,128,1024) f32, Wq/Wk (1024,1024) f32,
// la (1024), scalar (1), bias (1024). Outputs: context (16,64,1024) then
// scores (16,64,128), concatenated flat f32.
//
// Round-13: (1) GEMM staging via global_load_lds width=16 (m97 pattern):
// next-tile loads in flight under MFMA, vmcnt(0)+s_barrier per K-step.
// (2) B merged into A: last block per batch (atomicAdd counter) does softmax.
//  K0 cast+prep: q/k/Wq/Wk -> bf16; la2/Sla; zero cnt[16]
//  K1 gemm (64x64, gload_lds): aqE = exp2(ALPHA*q@Wq^T); akE = exp2(ALPHA*(Wk@keys^T+bias))
//  K2 scores: partials (pair-combined) + last-block softmax -> p_buf/out_scores
//  K3 ctx: p @ keys (LDS-staged)

#define ALPHA_2LOG2E 2.8853900817779268f
#define LOG2E 1.4426950408889634f

typedef __attribute__((ext_vector_type(8))) short short8;
typedef __attribute__((ext_vector_type(4))) float f32x4;
typedef __attribute__((ext_vector_type(2))) float f32x2;

static __device__ __forceinline__ short f2bf(float f) {
    union { float f; unsigned u; } v; v.f = f;
    unsigned r = v.u + 0x7fffu + ((v.u >> 16) & 1u);   // round-nearest-even
    return (short)(r >> 16);
}

// async global->LDS, 16B per lane; lds base must be wave-uniform (HW adds lane*16)
static __device__ __forceinline__ void gload16(const void* g, void* l) {
    __builtin_amdgcn_global_load_lds(
        (const __attribute__((address_space(1))) unsigned*)g,
        (__attribute__((address_space(3))) unsigned*)l, 16, 0, 0);
}

// ---------------- K0: fp32 -> bf16 cast, la prep + counter zero in last block ----------------
__global__ __launch_bounds__(256) void cast_prep_kernel(
    const float* __restrict__ q, const float* __restrict__ k,
    const float* __restrict__ wq, const float* __restrict__ wk,
    short* __restrict__ qb, short* __restrict__ kb,
    short* __restrict__ wqb, short* __restrict__ wkb,
    const float* __restrict__ la, const float* __restrict__ scal,
    float* __restrict__ la2, float* __restrict__ sla, int* __restrict__ cnt)
{
    const int bid = blockIdx.x;
    if (bid == 2560) {   // la prep + zero counters
        __shared__ float red[4];
        const int t = threadIdx.x, lane = t & 63, w = t >> 6;
        if (t < 16) cnt[t] = 0;
        float ss = 0.f;
        for (int i = t; i < 1024; i += 256) { float v = la[i]; ss = fmaf(v, v, ss); }
        #pragma unroll
        for (int off = 32; off; off >>= 1) ss += __shfl_xor(ss, off, 64);
        if (lane == 0) red[w] = ss;
        __syncthreads();
        const float tot = red[0] + red[1] + red[2] + red[3];
        const float sc = scal[0] / sqrtf(tot);
        float s2 = 0.f;
        for (int i = t; i < 1024; i += 256) {
            float v = la[i] * sc;
            la2[i] = 2.f * v;
            s2 += v;
        }
        #pragma unroll
        for (int off = 32; off; off >>= 1) s2 += __shfl_xor(s2, off, 64);
        __syncthreads();
        if (lane == 0) red[w] = s2;
        __syncthreads();
        if (t == 0) sla[0] = red[0] + red[1] + red[2] + red[3];
        return;
    }
    const float* src; short* dst; int base;
    if (bid < 512)       { src = q;  dst = qb;  base = bid; }
    else if (bid < 1536) { src = k;  dst = kb;  base = bid - 512; }
    else if (bid < 2048) { src = wq; dst = wqb; base = bid - 1536; }
    else                 { src = wk; dst = wkb; base = bid - 2048; }
    const size_t i = ((size_t)base * 256 + threadIdx.x) * 8;
    float4 a = *reinterpret_cast<const float4*>(src + i);
    float4 b = *reinterpret_cast<const float4*>(src + i + 4);
    short8 o;
    o[0] = f2bf(a.x); o[1] = f2bf(a.y); o[2] = f2bf(a.z); o[3] = f2bf(a.w);
    o[4] = f2bf(b.x); o[5] = f2bf(b.y); o[6] = f2bf(b.z); o[7] = f2bf(b.w);
    *reinterpret_cast<short8*>(dst + i) = o;
}

// ---------------- K1: bf16 MFMA NT-GEMM, 64x64 tile, global_load_lds staging ----------------
// bid < 256 : aqE = exp2(ALPHA*(qb @ wqb^T)),           ldc 1024
// bid >= 256: akE = exp2(ALPHA*(wkb @ kb^T + bias[m])), ldc 2048
// 256 thr = 4 waves (2x2); wave w stages rows [16w,16w+16) of each 64x32 tile
// (lds dest = tile base + w*1024 B, HW adds lane*16). Double-buffered;
// next-tile loads issued right after barrier, drained by vmcnt(0) at step end.
__global__ __launch_bounds__(256) void gemm_mfma_kernel(
    const short* __restrict__ qb, const short* __restrict__ kb,
    const short* __restrict__ wqb, const short* __restrict__ wkb,
    const float* __restrict__ bias,
    float* __restrict__ aqE, float* __restrict__ akE)
{
    __shared__ short As[2][64][32];
    __shared__ short Bs[2][64][32];

    const int bid = blockIdx.x;
    const short* A; const short* W; float* C; int useBias, bm, bn, ldc;
    if (bid < 256) {
        A = qb;  W = wqb; C = aqE; useBias = 0; ldc = 1024;
        bm = (bid & 15) * 64; bn = (bid >> 4) * 64;
    } else {
        int b2 = bid - 256;
        A = wkb; W = kb;  C = akE; useBias = 1; ldc = 2048;
        bm = (b2 & 15) * 64; bn = (b2 >> 4) * 64;
    }

    const int t = threadIdx.x;
    const int lane = t & 63, wid = t >> 6;
    const int wr = wid >> 1, wc = wid & 1;      // 2x2 waves -> 32x32 tiles
    const int fr = lane & 15, fg = lane >> 4;

    // per-lane global source: row = base + wid*16 + (lane>>2), k-slot = (lane&3)*8
    const short* gA0 = A + (size_t)(bm + (wid << 4) + (lane >> 2)) * 1024 + ((lane & 3) << 3);
    const short* gB0 = W + (size_t)(bn + (wid << 4) + (lane >> 2)) * 1024 + ((lane & 3) << 3);

    const f32x4 zero = {0.f, 0.f, 0.f, 0.f};
    f32x4 acc[2][2];
    acc[0][0] = zero; acc[0][1] = zero; acc[1][0] = zero; acc[1][1] = zero;

    // prologue: tile 0 -> buf 0
    gload16(gA0, &As[0][wid << 4][0]);
    gload16(gB0, &Bs[0][wid << 4][0]);
    asm volatile("s_waitcnt vmcnt(0)" ::: "memory");
    __builtin_amdgcn_s_barrier();
    asm volatile("" ::: "memory");

    #pragma unroll 1
    for (int kt = 0; kt < 32; ++kt) {
        const int cur = kt & 1;
        // issue next-tile loads into other buffer (in flight under the MFMAs)
        if (kt < 31) {
            const int ko = (kt + 1) << 5;
            gload16(gA0 + ko, &As[cur ^ 1][wid << 4][0]);
            gload16(gB0 + ko, &Bs[cur ^ 1][wid << 4][0]);
        }
        short8 af[2], bfr[2];
        #pragma unroll
        for (int mi = 0; mi < 2; ++mi)
            af[mi] = *(const short8*)&As[cur][wr * 32 + mi * 16 + fr][fg * 8];
        #pragma unroll
        for (int ni = 0; ni < 2; ++ni)
            bfr[ni] = *(const short8*)&Bs[cur][wc * 32 + ni * 16 + fr][fg * 8];
        #pragma unroll
        for (int mi = 0; mi < 2; ++mi)
            #pragma unroll
            for (int ni = 0; ni < 2; ++ni)
                acc[mi][ni] = __builtin_amdgcn_mfma_f32_16x16x32_bf16(
                    af[mi], bfr[ni], acc[mi][ni], 0, 0, 0);
        asm volatile("s_waitcnt vmcnt(0) lgkmcnt(0)" ::: "memory");
        __builtin_amdgcn_s_barrier();
        asm volatile("" ::: "memory");
    }

    // C/D: col=lane&15, row=(lane>>4)*4+reg; epilogue: exp2(ALPHA*(v+bias))
    float* Cb = C + (size_t)bm * ldc;
    #pragma unroll
    for (int mi = 0; mi < 2; ++mi) {
        const int row0 = wr * 32 + mi * 16 + fg * 4;
        float brow[4] = {0.f, 0.f, 0.f, 0.f};
        if (useBias) {
            #pragma unroll
            for (int r = 0; r < 4; ++r) brow[r] = bias[bm + row0 + r];
        }
        #pragma unroll
        for (int ni = 0; ni < 2; ++ni) {
            const int col = bn + wc * 32 + ni * 16 + fr;
            #pragma unroll
            for (int r = 0; r < 4; ++r)
                Cb[(size_t)(row0 + r) * ldc + col] =
                    __builtin_amdgcn_exp2f((acc[mi][ni][r] + brow[r]) * ALPHA_2LOG2E);
        }
    }
}

// ---------------- K2: scores partials + last-block softmax ----------------
// grid (16 b, 16 nc), 1024 thr (16 waves). A-phase: wave w -> q rows [4w,4w+4),
// lane -> k-pair {2l,2l+1}, pair-combined over n (1 rcp / 2 elems).
// Then: fence + atomicAdd(cnt[b]); 16th block sums partials, softmax,
// writes p_buf + out_scores (wave w -> q rows 4w..4w+3).
__global__ __launch_bounds__(1024) void scores_kernel(
    const float* __restrict__ aqE, const float* __restrict__ akE,
    const float* __restrict__ la2, const float* __restrict__ sla,
    float* __restrict__ partials, float* __restrict__ p_buf,
    float* __restrict__ out_scores, int* __restrict__ cnt)
{
    const int b = blockIdx.x, nc = blockIdx.y;
    const int t = threadIdx.x, w = t >> 6, lane = t & 63;

    __shared__ float eqs[64][64];    // [q][n]  16 KB
    __shared__ float eks[64][128];   // [n][k]  32 KB
    __shared__ float l2s[64];
    __shared__ int isLast;

    {
        const int qq = t >> 4, nj = (t & 15) << 2;
        *(float4*)&eqs[qq][nj] =
            *(const float4*)(aqE + ((size_t)((b << 6) + qq) << 10) + (nc << 6) + nj);
        const int n = t >> 4, k0 = (t & 15) << 3;
        const float* src = akE + ((size_t)((nc << 6) + n) << 11) + (b << 7) + k0;
        *(float4*)&eks[n][k0]     = *(const float4*)src;
        *(float4*)&eks[n][k0 + 4] = *(const float4*)(src + 4);
        if (t < 64) l2s[t] = la2[(nc << 6) + t];
    }
    __syncthreads();

    const int q0 = w << 2;
    f32x2 acc[4];
    #pragma unroll
    for (int i = 0; i < 4; ++i) acc[i] = (f32x2){0.f, 0.f};

    const int kb2 = lane << 1;
    #pragma unroll 4
    for (int np = 0; np < 32; ++np) {
        const int n0 = np << 1;
        const f32x2 ek0 = *(const f32x2*)&eks[n0][kb2];
        const f32x2 ek1 = *(const f32x2*)&eks[n0 + 1][kb2];
        const f32x2 l2 = *(const f32x2*)&l2s[n0];
        const float S = l2.x + l2.y;
        #pragma unroll
        for (int i = 0; i < 4; ++i) {
            const f32x2 eq = *(const f32x2*)&eqs[q0 + i][n0];
            const f32x2 E0 = eq.x * ek0;
            const f32x2 E1 = eq.y * ek1;
            const f32x2 d1 = E1 + 1.f;
            const f32x2 D  = E0 * d1 + d1;              // (1+E0)(1+E1)
            const f32x2 num = l2.x * E1 + (l2.y * E0 + S);
            f32x2 r;
            r.x = __builtin_amdgcn_rcpf(D.x);
            r.y = __builtin_amdgcn_rcpf(D.y);
            acc[i] = num * r + acc[i];
        }
    }

    float* pp = partials + ((size_t)((b << 4) + nc) << 13) + kb2;
    #pragma unroll
    for (int i = 0; i < 4; ++i)
        *(f32x2*)(pp + ((q0 + i) << 7)) = acc[i];

    // release partials, then count completion for this batch
    __threadfence();
    __syncthreads();
    if (t == 0) isLast = (atomicAdd(&cnt[b], 1) == 15);
    __syncthreads();
    if (!isLast) return;
    __threadfence();   // acquire: make all blocks' partials visible

    // B phase (last block only): wave w -> q rows 4w..4w+3
    const float Sla = sla[0];
    #pragma unroll
    for (int qi = 0; qi < 4; ++qi) {
        const int q = (w << 2) + qi;
        const float* pq = partials + ((size_t)b << 17) + (q << 7) + kb2;
        float s0 = 0.f, s1 = 0.f;
        #pragma unroll
        for (int c = 0; c < 16; ++c) {
            const float2 v = *(const float2*)(pq + ((size_t)c << 13));
            s0 += v.x; s1 += v.y;
        }
        s0 = Sla - s0; s1 = Sla - s1;
        float m = fmaxf(s0, s1);
        #pragma unroll
        for (int off = 32; off; off >>= 1) m = fmaxf(m, __shfl_xor(m, off, 64));
        float e0 = __builtin_amdgcn_exp2f((s0 - m) * LOG2E);
        float e1 = __builtin_amdgcn_exp2f((s1 - m) * LOG2E);
        float s = e0 + e1;
        #pragma unroll
        for (int off = 32; off; off >>= 1) s += __shfl_xor(s, off, 64);
        const float inv = __builtin_amdgcn_rcpf(s);
        float2 p = {e0 * inv, e1 * inv};
        *(float2*)(p_buf + ((size_t)((b << 6) + q) << 7) + kb2) = p;
        *(float2*)(out_scores + ((size_t)((b << 6) + q) << 7) + kb2) = p;
    }
}

// ---------------- K3: context = p @ keys (LDS-staged, keys read once) ----------------
__global__ __launch_bounds__(512) void ctx_kernel(
    const float* __restrict__ p_buf, const float* __restrict__ keys,
    float* __restrict__ ctx)
{
    const int b = blockIdx.x, nc = blockIdx.y;
    const int t = threadIdx.x;

    __shared__ float ks[128][64];   // [k][n] 32 KB
    __shared__ float ps[64][128];   // [q][k] 32 KB

    {
        const int k = t >> 2, n0 = (t & 3) << 4;
        const float* src = keys + ((size_t)((b << 7) + k) << 10) + (nc << 6) + n0;
        #pragma unroll
        for (int i = 0; i < 4; ++i)
            *(float4*)&ks[k][n0 + (i << 2)] = *(const float4*)(src + (i << 2));
        const int qq = t >> 3, k0 = (t & 7) << 4;
        const float* psrc = p_buf + ((size_t)((b << 6) + qq) << 7) + k0;
        #pragma unroll
        for (int i = 0; i < 4; ++i)
            *(float4*)&ps[qq][k0 + (i << 2)] = *(const float4*)(psrc + (i << 2));
    }
    __syncthreads();

    const int q0 = (t >> 5) << 2;
    const int n0 = (t & 31) << 1;
    float acc[4][2];
    #pragma unroll
    for (int i = 0; i < 4; ++i) { acc[i][0] = 0.f; acc[i][1] = 0.f; }

    #pragma unroll 8
    for (int k = 0; k < 128; ++k) {
        const float2 kv = *(const float2*)&ks[k][n0];
        #pragma unroll
        for (int i = 0; i < 4; ++i) {
            const float p = ps[q0 + i][k];
            acc[i][0] = fmaf(p, kv.x, acc[i][0]);
            acc[i][1] = fmaf(p, kv.y, acc[i][1]);
        }
    }
    #pragma unroll
    for (int i = 0; i < 4; ++i) {
        float2 v = {acc[i][0], acc[i][1]};
        *(float2*)(ctx + ((size_t)((b << 6) + q0 + i) << 10) + (nc << 6) + n0) = v;
    }
}

extern "C" void kernel_launch(void* const* d_in, const int* in_sizes, int n_in,
                              void* d_out, int out_size, void* d_ws, size_t ws_size,
                              hipStream_t stream) {
    const float* query  = (const float*)d_in[0];
    const float* keys   = (const float*)d_in[1];
    const float* Wq     = (const float*)d_in[2];
    const float* Wk     = (const float*)d_in[3];
    const float* la     = (const float*)d_in[4];
    const float* scal   = (const float*)d_in[5];
    const float* bias   = (const float*)d_in[6];

    float* ws  = (float*)d_ws;
    float* aqE = ws;                        // 1M f32 (4 MB)
    float* akE = ws + (1u << 20);           // 2M f32 (8 MB)
    float* la2 = akE + (2u << 20);          // 1024 f32
    float* sla = la2 + 1024;                // 1 f32
    int*   cnt = (int*)(sla + 1);           // 16 ints (zeroed each launch by K0)
    short* qb  = (short*)(ws + 3 * 1048576 + 2048);  // 1M bf16 (2 MB)
    short* kb  = qb + 1048576;                       // 2M bf16 (4 MB)
    short* wqb = kb + 2097152;                       // 1M bf16 (2 MB)
    short* wkb = wqb + 1048576;                      // 1M bf16 (2 MB)
    float* partials = (float*)kb;           // aliases kb..wkb (dead after gemm), 8 MB
    float* p_buf    = (float*)qb;           // aliases qb, 512 KB

    float* ctx        = (float*)d_out;
    float* out_scores = ctx + (size_t)16 * 64 * 1024;

    cast_prep_kernel<<<2561, 256, 0, stream>>>(query, keys, Wq, Wk, qb, kb, wqb, wkb,
                                               la, scal, la2, sla, cnt);
    gemm_mfma_kernel<<<768, 256, 0, stream>>>(qb, kb, wqb, wkb, bias, aqE, akE);
    scores_kernel<<<dim3(16, 16), 1024, 0, stream>>>(aqE, akE, la2, sla,
                                                     partials, p_buf, out_scores, cnt);
    ctx_kernel<<<dim3(16, 16), 512, 0, stream>>>(p_buf, keys, ctx);
}

// Round 14
// 59.629 us; speedup vs baseline: 2.8354x; 2.8354x over previous
//
#include <hip/hip_runtime.h>
#include <hip/hip_bf16.h>
#include <math.h>

// BahdanauAttention on MI355X (gfx950).
// query (16,64,1024) f32, keys (16,128,1024) f32, Wq/Wk (1024,1024) f32,
// la (1024), scalar (1), bias (1024). Outputs: context (16,64,1024) then
// scores (16,64,128), concatenated flat f32.
//
// Round-14: r13's global_load_lds GEMM (kept; ~14us faster than reg-staged)
// + r12's separate A/B scores kernels (r13's fence-based merge cost ~125us:
// device-scope __threadfence per block = L2 writeback on non-coherent XCDs).
//  K0 cast+prep: q/k/Wq/Wk -> bf16; la2/Sla
//  K1 gemm (64x64, gload_lds dbuf): aqE = exp2(ALPHA*q@Wq^T); akE = exp2(...)
//  A: partials (pair-combined, 1 rcp / 2 elems)
//  B: reduce + softmax -> p_buf + out_scores
//  C: ctx = p @ keys (LDS-staged)

#define ALPHA_2LOG2E 2.8853900817779268f
#define LOG2E 1.4426950408889634f

typedef __attribute__((ext_vector_type(8))) short short8;
typedef __attribute__((ext_vector_type(4))) float f32x4;
typedef __attribute__((ext_vector_type(2))) float f32x2;

static __device__ __forceinline__ short f2bf(float f) {
    union { float f; unsigned u; } v; v.f = f;
    unsigned r = v.u + 0x7fffu + ((v.u >> 16) & 1u);   // round-nearest-even
    return (short)(r >> 16);
}

// async global->LDS, 16B per lane; lds base wave-uniform (HW adds lane*16)
static __device__ __forceinline__ void gload16(const void* g, void* l) {
    __builtin_amdgcn_global_load_lds(
        (const __attribute__((address_space(1))) unsigned*)g,
        (__attribute__((address_space(3))) unsigned*)l, 16, 0, 0);
}

// ---------------- K0: fp32 -> bf16 cast, plus la prep in last block ----------------
__global__ __launch_bounds__(256) void cast_prep_kernel(
    const float* __restrict__ q, const float* __restrict__ k,
    const float* __restrict__ wq, const float* __restrict__ wk,
    short* __restrict__ qb, short* __restrict__ kb,
    short* __restrict__ wqb, short* __restrict__ wkb,
    const float* __restrict__ la, const float* __restrict__ scal,
    float* __restrict__ la2, float* __restrict__ sla)
{
    const int bid = blockIdx.x;
    if (bid == 2560) {   // la prep
        __shared__ float red[4];
        const int t = threadIdx.x, lane = t & 63, w = t >> 6;
        float ss = 0.f;
        for (int i = t; i < 1024; i += 256) { float v = la[i]; ss = fmaf(v, v, ss); }
        #pragma unroll
        for (int off = 32; off; off >>= 1) ss += __shfl_xor(ss, off, 64);
        if (lane == 0) red[w] = ss;
        __syncthreads();
        const float tot = red[0] + red[1] + red[2] + red[3];
        const float sc = scal[0] / sqrtf(tot);
        float s2 = 0.f;
        for (int i = t; i < 1024; i += 256) {
            float v = la[i] * sc;
            la2[i] = 2.f * v;
            s2 += v;
        }
        #pragma unroll
        for (int off = 32; off; off >>= 1) s2 += __shfl_xor(s2, off, 64);
        __syncthreads();
        if (lane == 0) red[w] = s2;
        __syncthreads();
        if (t == 0) sla[0] = red[0] + red[1] + red[2] + red[3];
        return;
    }
    const float* src; short* dst; int base;
    if (bid < 512)       { src = q;  dst = qb;  base = bid; }
    else if (bid < 1536) { src = k;  dst = kb;  base = bid - 512; }
    else if (bid < 2048) { src = wq; dst = wqb; base = bid - 1536; }
    else                 { src = wk; dst = wkb; base = bid - 2048; }
    const size_t i = ((size_t)base * 256 + threadIdx.x) * 8;
    float4 a = *reinterpret_cast<const float4*>(src + i);
    float4 b = *reinterpret_cast<const float4*>(src + i + 4);
    short8 o;
    o[0] = f2bf(a.x); o[1] = f2bf(a.y); o[2] = f2bf(a.z); o[3] = f2bf(a.w);
    o[4] = f2bf(b.x); o[5] = f2bf(b.y); o[6] = f2bf(b.z); o[7] = f2bf(b.w);
    *reinterpret_cast<short8*>(dst + i) = o;
}

// ---------------- K1: bf16 MFMA NT-GEMM, 64x64 tile, global_load_lds staging ----------------
__global__ __launch_bounds__(256) void gemm_mfma_kernel(
    const short* __restrict__ qb, const short* __restrict__ kb,
    const short* __restrict__ wqb, const short* __restrict__ wkb,
    const float* __restrict__ bias,
    float* __restrict__ aqE, float* __restrict__ akE)
{
    __shared__ short As[2][64][32];
    __shared__ short Bs[2][64][32];

    const int bid = blockIdx.x;
    const short* A; const short* W; float* C; int useBias, bm, bn, ldc;
    if (bid < 256) {
        A = qb;  W = wqb; C = aqE; useBias = 0; ldc = 1024;
        bm = (bid & 15) * 64; bn = (bid >> 4) * 64;
    } else {
        int b2 = bid - 256;
        A = wkb; W = kb;  C = akE; useBias = 1; ldc = 2048;
        bm = (b2 & 15) * 64; bn = (b2 >> 4) * 64;
    }

    const int t = threadIdx.x;
    const int lane = t & 63, wid = t >> 6;
    const int wr = wid >> 1, wc = wid & 1;      // 2x2 waves -> 32x32 tiles
    const int fr = lane & 15, fg = lane >> 4;

    // per-lane global source: row = base + wid*16 + (lane>>2), k-slot = (lane&3)*8
    const short* gA0 = A + (size_t)(bm + (wid << 4) + (lane >> 2)) * 1024 + ((lane & 3) << 3);
    const short* gB0 = W + (size_t)(bn + (wid << 4) + (lane >> 2)) * 1024 + ((lane & 3) << 3);

    const f32x4 zero = {0.f, 0.f, 0.f, 0.f};
    f32x4 acc[2][2];
    acc[0][0] = zero; acc[0][1] = zero; acc[1][0] = zero; acc[1][1] = zero;

    // prologue: tile 0 -> buf 0
    gload16(gA0, &As[0][wid << 4][0]);
    gload16(gB0, &Bs[0][wid << 4][0]);
    asm volatile("s_waitcnt vmcnt(0)" ::: "memory");
    __builtin_amdgcn_s_barrier();
    asm volatile("" ::: "memory");

    #pragma unroll 1
    for (int kt = 0; kt < 32; ++kt) {
        const int cur = kt & 1;
        if (kt < 31) {
            const int ko = (kt + 1) << 5;
            gload16(gA0 + ko, &As[cur ^ 1][wid << 4][0]);
            gload16(gB0 + ko, &Bs[cur ^ 1][wid << 4][0]);
        }
        short8 af[2], bfr[2];
        #pragma unroll
        for (int mi = 0; mi < 2; ++mi)
            af[mi] = *(const short8*)&As[cur][wr * 32 + mi * 16 + fr][fg * 8];
        #pragma unroll
        for (int ni = 0; ni < 2; ++ni)
            bfr[ni] = *(const short8*)&Bs[cur][wc * 32 + ni * 16 + fr][fg * 8];
        #pragma unroll
        for (int mi = 0; mi < 2; ++mi)
            #pragma unroll
            for (int ni = 0; ni < 2; ++ni)
                acc[mi][ni] = __builtin_amdgcn_mfma_f32_16x16x32_bf16(
                    af[mi], bfr[ni], acc[mi][ni], 0, 0, 0);
        asm volatile("s_waitcnt vmcnt(0) lgkmcnt(0)" ::: "memory");
        __builtin_amdgcn_s_barrier();
        asm volatile("" ::: "memory");
    }

    // C/D: col=lane&15, row=(lane>>4)*4+reg; epilogue: exp2(ALPHA*(v+bias))
    float* Cb = C + (size_t)bm * ldc;
    #pragma unroll
    for (int mi = 0; mi < 2; ++mi) {
        const int row0 = wr * 32 + mi * 16 + fg * 4;
        float brow[4] = {0.f, 0.f, 0.f, 0.f};
        if (useBias) {
            #pragma unroll
            for (int r = 0; r < 4; ++r) brow[r] = bias[bm + row0 + r];
        }
        #pragma unroll
        for (int ni = 0; ni < 2; ++ni) {
            const int col = bn + wc * 32 + ni * 16 + fr;
            #pragma unroll
            for (int r = 0; r < 4; ++r)
                Cb[(size_t)(row0 + r) * ldc + col] =
                    __builtin_amdgcn_exp2f((acc[mi][ni][r] + brow[r]) * ALPHA_2LOG2E);
        }
    }
}

// ---------------- A: scores partials, pair-combined over n ----------------
// grid (16 b, 16 nc), 1024 thr (16 waves). Wave w -> q rows [4w,4w+4);
// lane -> k-pair {2l, 2l+1} packed f32x2. 1 rcp / 2 elements.
__global__ __launch_bounds__(1024) void scores_part_kernel(
    const float* __restrict__ aqE, const float* __restrict__ akE,
    const float* __restrict__ la2, float* __restrict__ partials)
{
    const int b = blockIdx.x, nc = blockIdx.y;
    const int t = threadIdx.x, w = t >> 6, lane = t & 63;

    __shared__ float eqs[64][64];    // [q][n]  16 KB
    __shared__ float eks[64][128];   // [n][k]  32 KB
    __shared__ float l2s[64];

    {
        const int qq = t >> 4, nj = (t & 15) << 2;
        *(float4*)&eqs[qq][nj] =
            *(const float4*)(aqE + ((size_t)((b << 6) + qq) << 10) + (nc << 6) + nj);
        const int n = t >> 4, k0 = (t & 15) << 3;
        const float* src = akE + ((size_t)((nc << 6) + n) << 11) + (b << 7) + k0;
        *(float4*)&eks[n][k0]     = *(const float4*)src;
        *(float4*)&eks[n][k0 + 4] = *(const float4*)(src + 4);
        if (t < 64) l2s[t] = la2[(nc << 6) + t];
    }
    __syncthreads();

    const int q0 = w << 2;
    f32x2 acc[4];
    #pragma unroll
    for (int i = 0; i < 4; ++i) acc[i] = (f32x2){0.f, 0.f};

    const int kb2 = lane << 1;
    #pragma unroll 4
    for (int np = 0; np < 32; ++np) {
        const int n0 = np << 1;
        const f32x2 ek0 = *(const f32x2*)&eks[n0][kb2];
        const f32x2 ek1 = *(const f32x2*)&eks[n0 + 1][kb2];
        const f32x2 l2 = *(const f32x2*)&l2s[n0];       // broadcast
        const float S = l2.x + l2.y;
        #pragma unroll
        for (int i = 0; i < 4; ++i) {
            const f32x2 eq = *(const f32x2*)&eqs[q0 + i][n0];   // broadcast
            const f32x2 E0 = eq.x * ek0;
            const f32x2 E1 = eq.y * ek1;
            const f32x2 d1 = E1 + 1.f;
            const f32x2 D  = E0 * d1 + d1;              // (1+E0)(1+E1)
            const f32x2 num = l2.x * E1 + (l2.y * E0 + S);
            f32x2 r;
            r.x = __builtin_amdgcn_rcpf(D.x);
            r.y = __builtin_amdgcn_rcpf(D.y);
            acc[i] = num * r + acc[i];
        }
    }

    float* pp = partials + ((size_t)((b << 4) + nc) << 13) + kb2;
    #pragma unroll
    for (int i = 0; i < 4; ++i)
        *(f32x2*)(pp + ((q0 + i) << 7)) = acc[i];
}

// ---------------- B: reduce partials + softmax ----------------
__global__ __launch_bounds__(256) void reduce_softmax_kernel(
    const float* __restrict__ partials, const float* __restrict__ sla,
    float* __restrict__ p_buf, float* __restrict__ out_scores)
{
    const int b = blockIdx.x, qo = blockIdx.y;
    const int t = threadIdx.x, w = t >> 6, lane = t & 63;
    const int q = (qo << 2) + w;

    const float* pp = partials + ((size_t)b << 17) + (q << 7) + (lane << 1);
    float s0 = 0.f, s1 = 0.f;
    #pragma unroll
    for (int nc = 0; nc < 16; ++nc) {
        const float2 v = *(const float2*)(pp + ((size_t)nc << 13));
        s0 += v.x; s1 += v.y;
    }
    const float Sla = sla[0];
    s0 = Sla - s0; s1 = Sla - s1;
    float m = fmaxf(s0, s1);
    #pragma unroll
    for (int off = 32; off; off >>= 1) m = fmaxf(m, __shfl_xor(m, off, 64));
    float e0 = __builtin_amdgcn_exp2f((s0 - m) * LOG2E);
    float e1 = __builtin_amdgcn_exp2f((s1 - m) * LOG2E);
    float s = e0 + e1;
    #pragma unroll
    for (int off = 32; off; off >>= 1) s += __shfl_xor(s, off, 64);
    const float inv = __builtin_amdgcn_rcpf(s);
    float2 p = {e0 * inv, e1 * inv};
    *(float2*)(p_buf + ((size_t)((b << 6) + q) << 7) + (lane << 1)) = p;
    *(float2*)(out_scores + ((size_t)((b << 6) + q) << 7) + (lane << 1)) = p;
}

// ---------------- C: context = p @ keys (LDS-staged, keys read once) ----------------
__global__ __launch_bounds__(512) void ctx_kernel(
    const float* __restrict__ p_buf, const float* __restrict__ keys,
    float* __restrict__ ctx)
{
    const int b = blockIdx.x, nc = blockIdx.y;
    const int t = threadIdx.x;

    __shared__ float ks[128][64];   // [k][n] 32 KB
    __shared__ float ps[64][128];   // [q][k] 32 KB

    {
        const int k = t >> 2, n0 = (t & 3) << 4;
        const float* src = keys + ((size_t)((b << 7) + k) << 10) + (nc << 6) + n0;
        #pragma unroll
        for (int i = 0; i < 4; ++i)
            *(float4*)&ks[k][n0 + (i << 2)] = *(const float4*)(src + (i << 2));
        const int qq = t >> 3, k0 = (t & 7) << 4;
        const float* psrc = p_buf + ((size_t)((b << 6) + qq) << 7) + k0;
        #pragma unroll
        for (int i = 0; i < 4; ++i)
            *(float4*)&ps[qq][k0 + (i << 2)] = *(const float4*)(psrc + (i << 2));
    }
    __syncthreads();

    const int q0 = (t >> 5) << 2;
    const int n0 = (t & 31) << 1;
    float acc[4][2];
    #pragma unroll
    for (int i = 0; i < 4; ++i) { acc[i][0] = 0.f; acc[i][1] = 0.f; }

    #pragma unroll 8
    for (int k = 0; k < 128; ++k) {
        const float2 kv = *(const float2*)&ks[k][n0];
        #pragma unroll
        for (int i = 0; i < 4; ++i) {
            const float p = ps[q0 + i][k];
            acc[i][0] = fmaf(p, kv.x, acc[i][0]);
            acc[i][1] = fmaf(p, kv.y, acc[i][1]);
        }
    }
    #pragma unroll
    for (int i = 0; i < 4; ++i) {
        float2 v = {acc[i][0], acc[i][1]};
        *(float2*)(ctx + ((size_t)((b << 6) + q0 + i) << 10) + (nc << 6) + n0) = v;
    }
}

extern "C" void kernel_launch(void* const* d_in, const int* in_sizes, int n_in,
                              void* d_out, int out_size, void* d_ws, size_t ws_size,
                              hipStream_t stream) {
    const float* query  = (const float*)d_in[0];
    const float* keys   = (const float*)d_in[1];
    const float* Wq     = (const float*)d_in[2];
    const float* Wk     = (const float*)d_in[3];
    const float* la     = (const float*)d_in[4];
    const float* scal   = (const float*)d_in[5];
    const float* bias   = (const float*)d_in[6];

    float* ws  = (float*)d_ws;
    float* aqE = ws;                        // 1M f32 (4 MB)
    float* akE = ws + (1u << 20);           // 2M f32 (8 MB)
    float* la2 = akE + (2u << 20);          // 1024 f32
    float* sla = la2 + 1024;                // 1 f32
    short* qb  = (short*)(ws + 3 * 1048576 + 2048);  // 1M bf16 (2 MB)
    short* kb  = qb + 1048576;                       // 2M bf16 (4 MB)
    short* wqb = kb + 2097152;                       // 1M bf16 (2 MB)
    short* wkb = wqb + 1048576;                      // 1M bf16 (2 MB)
    float* partials = (float*)kb;           // aliases kb..wkb (dead after gemm), 8 MB
    float* p_buf    = (float*)qb;           // aliases qb, 512 KB

    float* ctx        = (float*)d_out;
    float* out_scores = ctx + (size_t)16 * 64 * 1024;

    cast_prep_kernel<<<2561, 256, 0, stream>>>(query, keys, Wq, Wk, qb, kb, wqb, wkb,
                                               la, scal, la2, sla);
    gemm_mfma_kernel<<<768, 256, 0, stream>>>(qb, kb, wqb, wkb, bias, aqE, akE);
    scores_part_kernel<<<dim3(16, 16), 1024, 0, stream>>>(aqE, akE, la2, partials);
    reduce_softmax_kernel<<<dim3(16, 16), 256, 0, stream>>>(partials, sla, p_buf, out_scores);
    ctx_kernel<<<dim3(16, 16), 512, 0, stream>>>(p_buf, keys, ctx);
}